// Round 1
// baseline (897.325 us; speedup 1.0000x reference)
//
#include <hip/hip_runtime.h>

// VLLMKVCache: out = cache; out[block_indices[t], block_offset[t], :, :] = input[t, :, :]
// cache/out: (1024, 128, 8, 128) f32 -> token row = contiguous 1024 floats (4 KiB), 512 MiB total
// input:     (8192, 8, 128) f32     -> token row = contiguous 1024 floats (4 KiB), 32 MiB total
//
// Key change vs previous version: hipMemcpyAsync D2D was being lowered to an
// SDMA copy node under graph capture (~1.2 TB/s effective -> ~700us of the
// 877us total). Replaced with a grid-stride float4 compute copy, which runs
// at the same ~6.3 TB/s the harness's fillBufferAligned achieves.

__global__ __launch_bounds__(256) void bulk_copy_kernel(const float4* __restrict__ src,
                                                        float4* __restrict__ dst,
                                                        size_t n4) {
    size_t i = (size_t)blockIdx.x * (size_t)blockDim.x + threadIdx.x;
    const size_t stride = (size_t)gridDim.x * (size_t)blockDim.x;
    for (; i < n4; i += stride) {
        dst[i] = src[i];
    }
}

// One workgroup per token: 256 threads x float4 = 1024 floats = one 4 KiB row.
__global__ __launch_bounds__(256) void kv_scatter_kernel(const float* __restrict__ inp,
                                                         float* __restrict__ out,
                                                         const int* __restrict__ block_indices,
                                                         const int* __restrict__ block_offset,
                                                         int row_elems /*=1024*/,
                                                         int block_size /*=128*/) {
    const int t = blockIdx.x;                 // token index
    const int bi = block_indices[t];
    const int bo = block_offset[t];
    const float4* __restrict__ src =
        (const float4*)(inp + (size_t)t * row_elems);
    float4* __restrict__ dst =
        (float4*)(out + ((size_t)bi * block_size + bo) * (size_t)row_elems);
    dst[threadIdx.x] = src[threadIdx.x];
}

extern "C" void kernel_launch(void* const* d_in, const int* in_sizes, int n_in,
                              void* d_out, int out_size, void* d_ws, size_t ws_size,
                              hipStream_t stream) {
    const float* inp           = (const float*)d_in[0];
    const float* cache         = (const float*)d_in[1];
    // d_in[2] = num_kv_cache_passes (scalar), d_in[3] = num_slots_available (scalar)
    const int*   block_indices = (const int*)d_in[4];
    const int*   block_offset  = (const int*)d_in[5];
    float* out = (float*)d_out;

    const int num_tokens = in_sizes[4];              // 8192
    const int row_elems  = in_sizes[0] / num_tokens; // 8*128 = 1024
    const int block_size = 128;                      // BLOCK_SIZE from reference

    // 1) Bulk copy cache -> out (512 MiB) with a compute blit at HBM rate.
    //    Grid: 2048 workgroups x 256 threads = 8 wg/CU on 256 CUs (full
    //    occupancy for an 8-VGPR kernel); each thread moves 64 float4s.
    const size_t n4 = (size_t)out_size / 4;          // float4 count
    const int copy_blocks = 2048;
    bulk_copy_kernel<<<copy_blocks, 256, 0, stream>>>(
        (const float4*)cache, (float4*)out, n4);

    // 2) Scatter the 8192 token rows (4 KiB each, fully coalesced).
    //    Stream-ordered after the copy, so scattered rows land last.
    kv_scatter_kernel<<<num_tokens, 256, 0, stream>>>(
        inp, out, block_indices, block_offset, row_elems, block_size);
}